// Round 10
// baseline (238.487 us; speedup 1.0000x reference)
//
#include <hip/hip_runtime.h>
#include <hip/hip_bf16.h>

#define BB 8
#define SS 2048
#define DD 384
#define HH 8
#define HD 48
#define QT 32
#define KT 32

typedef unsigned short u16;
typedef unsigned int u32;
typedef unsigned short u16x4 __attribute__((ext_vector_type(4)));
typedef unsigned short u16x8 __attribute__((ext_vector_type(8)));
typedef unsigned int u32x2 __attribute__((ext_vector_type(2)));
typedef short s16x8 __attribute__((ext_vector_type(8)));
typedef float f32x4 __attribute__((ext_vector_type(4)));

__device__ __forceinline__ float bf2f(u16 v){
  union { u32 u; float f; } x; x.u = ((u32)v) << 16; return x.f;
}
__device__ __forceinline__ u16 f2bf(float f){
  union { float f; u32 u; } x; x.f = f;
  u32 r = x.u + 0x7fffu + ((x.u >> 16) & 1u);
  return (u16)(r >> 16);
}
// split fp32 into hi (truncated bf16) + lo (bf16 of residual); hi+lo ~ 17-bit mantissa
__device__ __forceinline__ void split2(float f, u16& h, u16& l){
  union { float f; u32 u; } x; x.f = f;
  h = (u16)(x.u >> 16);
  l = f2bf(f - bf2f(h));
}
// pack two f32 -> two truncated bf16 in one u32 (lo = a, hi = b)
__device__ __forceinline__ u32 pack_trunc2(float a, float b){
  union { float f; u32 u; } xa, xb; xa.f = a; xb.f = b;
  return (xa.u >> 16) | (xb.u & 0xffff0000u);
}

// lgkm-only barrier: LDS writes visible, but global loads stay in flight
#define LBAR() do { \
  asm volatile("s_waitcnt lgkmcnt(0)" ::: "memory"); \
  __builtin_amdgcn_s_barrier(); \
  asm volatile("" ::: "memory"); \
} while (0)

// ---------------- Kernel 1: QKV projection, split-bf16 MFMA GEMM ----------------
// C[16384 x 1152] = x[16384 x 384] * Wqkv^T ; scatter to Q (pre-scaled by
// log2(e)/sqrt(48) so attn softmax can use exp2), K ([B,H,S,48]) and
// V^T ([B,H,48,S]) bf16 with bias.
__global__ __launch_bounds__(512, 4) void qkv_gemm(
    const float* __restrict__ x, const float* __restrict__ W,
    const float* __restrict__ bias,
    u16* __restrict__ Q, u16* __restrict__ Kd, u16* __restrict__ Vt)
{
  __shared__ u16 Ah[128][40], Al[128][40], Bh[128][40], Bl[128][40];
  const int tid  = threadIdx.x;
  const int w    = tid >> 6, lane = tid & 63;
  const int lg   = lane >> 4, ln = lane & 15;
  const int wm   = w >> 1, wn = w & 1;
  const int mb   = blockIdx.x / 9, nb = blockIdx.x % 9;
  const int m0   = mb * 128, n0 = nb * 128;
  const int srow = tid >> 3, sk4 = (tid & 7) << 2;
  const float qscale = 0.2082350972f;  // log2(e)/sqrt(48)

  f32x4 acc[8];
  #pragma unroll
  for (int i = 0; i < 8; i++) acc[i] = (f32x4){0.f,0.f,0.f,0.f};

  for (int ks = 0; ks < 12; ks++){
    const int k0 = ks * 32;
    __syncthreads();
    #pragma unroll
    for (int p = 0; p < 2; p++){
      const int row = srow + p*64;
      float4 av = *(const float4*)(x + (long)(m0+row)*DD + k0 + sk4);
      float4 bv = *(const float4*)(W + (long)(n0+row)*DD + k0 + sk4);
      u16 h0,l0,h1,l1,h2,l2,h3,l3;
      split2(av.x,h0,l0); split2(av.y,h1,l1); split2(av.z,h2,l2); split2(av.w,h3,l3);
      *(u16x4*)&Ah[row][sk4] = (u16x4){h0,h1,h2,h3};
      *(u16x4*)&Al[row][sk4] = (u16x4){l0,l1,l2,l3};
      split2(bv.x,h0,l0); split2(bv.y,h1,l1); split2(bv.z,h2,l2); split2(bv.w,h3,l3);
      *(u16x4*)&Bh[row][sk4] = (u16x4){h0,h1,h2,h3};
      *(u16x4*)&Bl[row][sk4] = (u16x4){l0,l1,l2,l3};
    }
    __syncthreads();
    s16x8 bh[4], bl[4];
    #pragma unroll
    for (int fn = 0; fn < 4; fn++){
      const int br = wn*64 + fn*16 + ln;
      bh[fn] = *(const s16x8*)&Bh[br][lg*8];
      bl[fn] = *(const s16x8*)&Bl[br][lg*8];
    }
    #pragma unroll
    for (int fm = 0; fm < 2; fm++){
      const int ar = wm*32 + fm*16 + ln;
      s16x8 ah = *(const s16x8*)&Ah[ar][lg*8];
      s16x8 al = *(const s16x8*)&Al[ar][lg*8];
      #pragma unroll
      for (int fn = 0; fn < 4; fn++){
        f32x4 c = acc[fm*4+fn];
        c = __builtin_amdgcn_mfma_f32_16x16x32_bf16(ah, bh[fn], c, 0, 0, 0);
        c = __builtin_amdgcn_mfma_f32_16x16x32_bf16(ah, bl[fn], c, 0, 0, 0);
        c = __builtin_amdgcn_mfma_f32_16x16x32_bf16(al, bh[fn], c, 0, 0, 0);
        acc[fm*4+fn] = c;
      }
    }
  }
  // epilogue: row = lg*4+r (M=token), col = ln (N=e); scatter
  #pragma unroll
  for (int fm = 0; fm < 2; fm++){
    #pragma unroll
    for (int fn = 0; fn < 4; fn++){
      const int e = n0 + wn*64 + fn*16 + ln;
      const float bi = bias[e];
      const int h = e / 144, c = e % 144;
      #pragma unroll
      for (int r = 0; r < 4; r++){
        const int mm = m0 + wm*32 + fm*16 + lg*4 + r;
        const int bb = mm >> 11, s = mm & 2047;
        const float v = acc[fm*4+fn][r] + bi;
        if (c < 48){
          Q[(((long)(bb*HH + h))*SS + s)*HD + c] = f2bf(v * qscale);
        } else if (c < 96){
          Kd[(((long)(bb*HH + h))*SS + s)*HD + (c-48)] = f2bf(v);
        } else {
          // V transposed: [B,H,48,S]
          Vt[(((long)(bb*HH + h))*HD + (c-96))*SS + s] = f2bf(v);
        }
      }
    }
  }
}

// ---------------- Kernel 2: MFMA attention with head-softmax ----------------
// Proven round-6/9 structure + OPTIONAL 2-way key split (ks_bits=1):
// head-softmax is per-(q,k) with no cross-k coupling, so each block handles
// SS/nks keys and writes a partial O sum to vals + ks*QSZ; out_gemm adds the
// partials (linear). Grid 8*64*nks blocks; 4 blocks/CU at nks=2 (LDS 4x40KB).
__global__ __launch_bounds__(512, 4) void attn_kernel(
    const u16* __restrict__ Q, const u16* __restrict__ K,
    const u16* __restrict__ Vg, float* __restrict__ vals, const int ks_bits)
{
  __shared__ u16 Ss[HH][QT][40];   // bf16 scores [h][q][k], 80B rows
  __shared__ u16 Pb[HH][QT][40];   // bf16 P [h][q][k], 80B rows

  const int tid  = threadIdx.x;
  const int h    = tid >> 6;
  const int lane = tid & 63;
  // XCD-chunked swizzle: batch b lives on XCD b (grid = 8 * 64 * nks).
  const int b    = (int)blockIdx.x & 7;
  const int rem  = (int)blockIdx.x >> 3;
  const int qt   = rem >> ks_bits;
  const int ks   = rem & ((1 << ks_bits) - 1);
  const int koff = ks << (11 - ks_bits);     // SS = 2048 = 1<<11
  const int nit2 = 32 >> ks_bits;            // (SS/nks)/KT/2 double-steps
  const int q0   = qt * QT;
  const int lg   = lane >> 4;
  const int ln   = lane & 15;

  const long hbase = ((long)(b*HH + h)) * SS;
  const u16* vbase = Vg + ((long)(b*HH + h)) * HD * SS;
  const s16x8 z8 = (s16x8){0,0,0,0,0,0,0,0};

  // Q fragments (B operand of swapped QK^T) for both subtiles, held all kernel.
  s16x8 qf0[2], qf1[2];
  #pragma unroll
  for (int qs = 0; qs < 2; qs++){
    const u16* qp = Q + (hbase + q0 + qs*16 + ln)*HD;
    qf0[qs] = *(const s16x8*)(qp + lg*8);
    if (lane < 32) qf1[qs] = *(const s16x8*)(qp + 32 + lg*8);
    else           qf1[qs] = z8;
  }

  f32x4 oacc[2][3];
  #pragma unroll
  for (int qs = 0; qs < 2; qs++)
    #pragma unroll
    for (int c = 0; c < 3; c++) oacc[qs][c] = (f32x4){0.f,0.f,0.f,0.f};

  // softmax mapping: thread owns (q = tid>>4, k = smk, smk+1)
  const int smq = tid >> 4, smk = (tid & 15) << 1;

  // K fragment double buffer: [buf][nt]; A = d0..31 slice, B = d32..47+pad
  s16x8 kfA[2][2], kfB[2][2];
  int k0 = koff;
  #pragma unroll
  for (int nt = 0; nt < 2; nt++){
    const u16* kp = K + (hbase + koff + nt*16 + ln)*HD;
    kfA[0][nt] = *(const s16x8*)(kp + lg*8);
    if (lane < 32) kfB[0][nt] = *(const s16x8*)(kp + 32 + lg*8);
    else           kfB[0][nt] = z8;
  }

#define STEP(CUR, NXT) { \
    /* V(t) fragments: issued now, consumed after both barriers */ \
    s16x8 vf0 = *(const s16x8*)(vbase + (long)(     ln)*SS + k0 + lg*8); \
    s16x8 vf1 = *(const s16x8*)(vbase + (long)(16 + ln)*SS + k0 + lg*8); \
    s16x8 vf2 = *(const s16x8*)(vbase + (long)(32 + ln)*SS + k0 + lg*8); \
    /* K(t+1) prefetch into buf NXT (wraps harmlessly on last iter) */ \
    const int knx = (k0 + KT) & (SS - 1); \
    _Pragma("unroll") \
    for (int nt = 0; nt < 2; nt++){ \
      const u16* kp = K + (hbase + knx + nt*16 + ln)*HD; \
      kfA[NXT][nt] = *(const s16x8*)(kp + lg*8); \
      if (lane < 32) kfB[NXT][nt] = *(const s16x8*)(kp + 32 + lg*8); \
      else           kfB[NXT][nt] = z8; \
    } \
    /* QK^T (swapped): D[k][q] from buf CUR; packed bf16 score writes */ \
    __builtin_amdgcn_s_setprio(1); \
    _Pragma("unroll") \
    for (int nt = 0; nt < 2; nt++){ \
      _Pragma("unroll") \
      for (int qs = 0; qs < 2; qs++){ \
        f32x4 a = (f32x4){0.f,0.f,0.f,0.f}; \
        a = __builtin_amdgcn_mfma_f32_16x16x32_bf16(kfA[CUR][nt], qf0[qs], a, 0, 0, 0); \
        a = __builtin_amdgcn_mfma_f32_16x16x32_bf16(kfB[CUR][nt], qf1[qs], a, 0, 0, 0); \
        u32x2 pw; pw[0] = pack_trunc2(a[0], a[1]); pw[1] = pack_trunc2(a[2], a[3]); \
        *(u32x2*)&Ss[h][qs*16 + ln][nt*16 + lg*4] = pw; \
      } \
    } \
    __builtin_amdgcn_s_setprio(0); \
    LBAR();   /* Ss visible; orders prev PV Pb-reads vs softmax writes */ \
    /* softmax over 8 heads; thread owns (smq, smk..smk+1), packed I/O */ \
    { \
      float e0[8], e1[8]; \
      float sum0 = 0.f, sum1 = 0.f; \
      _Pragma("unroll") \
      for (int hh = 0; hh < 8; hh++){ \
        u32 wv = *(const u32*)&Ss[hh][smq][smk]; \
        union { u32 u; float f; } a0, a1; \
        a0.u = wv << 16; a1.u = wv & 0xffff0000u; \
        e0[hh] = __builtin_amdgcn_exp2f(a0.f); \
        e1[hh] = __builtin_amdgcn_exp2f(a1.f); \
        sum0 += e0[hh]; sum1 += e1[hh]; \
      } \
      float r0 = __builtin_amdgcn_rcpf(sum0); \
      float r1 = __builtin_amdgcn_rcpf(sum1); \
      _Pragma("unroll") \
      for (int hh = 0; hh < 8; hh++) \
        *(u32*)&Pb[hh][smq][smk] = pack_trunc2(e0[hh]*r0, e1[hh]*r1); \
    } \
    LBAR();   /* Pb visible; orders softmax Ss-reads vs next-iter writes */ \
    __builtin_amdgcn_s_setprio(1); \
    _Pragma("unroll") \
    for (int qs = 0; qs < 2; qs++){ \
      s16x8 pf = *(const s16x8*)&Pb[h][qs*16 + ln][lg*8]; \
      oacc[qs][0] = __builtin_amdgcn_mfma_f32_16x16x32_bf16(pf, vf0, oacc[qs][0], 0, 0, 0); \
      oacc[qs][1] = __builtin_amdgcn_mfma_f32_16x16x32_bf16(pf, vf1, oacc[qs][1], 0, 0, 0); \
      oacc[qs][2] = __builtin_amdgcn_mfma_f32_16x16x32_bf16(pf, vf2, oacc[qs][2], 0, 0, 0); \
    } \
    __builtin_amdgcn_s_setprio(0); \
    k0 = knx; \
  }

  for (int kt2 = 0; kt2 < nit2; kt2++){
    STEP(0, 1)
    STEP(1, 0)
  }
#undef STEP

  // store partial O to vals + ks*QSZ (bug-compatible flat layout per buffer)
  float* op = vals + (size_t)ks * ((size_t)BB*HH*SS*HD) + (hbase + q0)*HD;
  #pragma unroll
  for (int qs = 0; qs < 2; qs++)
    #pragma unroll
    for (int c = 0; c < 3; c++)
      #pragma unroll
      for (int r = 0; r < 4; r++)
        op[(long)(qs*16 + lg*4 + r)*HD + c*16 + ln] = oacc[qs][c][r];
}

// ---------------- Kernel 3: output projection, split-bf16 MFMA GEMM ----------------
// A2 (nullable): second partial-sum buffer from the k-split attention.
__global__ __launch_bounds__(512, 4) void out_gemm(
    const float* __restrict__ A, const float* __restrict__ A2,
    const float* __restrict__ W,
    const float* __restrict__ bias, float* __restrict__ out)
{
  __shared__ u16 Ah[128][40], Al[128][40], Bh[128][40], Bl[128][40];
  const int tid  = threadIdx.x;
  const int w    = tid >> 6, lane = tid & 63;
  const int lg   = lane >> 4, ln = lane & 15;
  const int wm   = w >> 1, wn = w & 1;
  const int mb   = blockIdx.x / 3, nb = blockIdx.x % 3;
  const int m0   = mb * 128, n0 = nb * 128;
  const int srow = tid >> 3, sk4 = (tid & 7) << 2;

  f32x4 acc[8];
  #pragma unroll
  for (int i = 0; i < 8; i++) acc[i] = (f32x4){0.f,0.f,0.f,0.f};

  for (int ks = 0; ks < 12; ks++){
    const int k0 = ks * 32;
    __syncthreads();
    #pragma unroll
    for (int p = 0; p < 2; p++){
      const int row = srow + p*64;
      const long aoff = (long)(m0+row)*DD + k0 + sk4;
      float4 av = *(const float4*)(A + aoff);
      if (A2){
        float4 a2 = *(const float4*)(A2 + aoff);
        av.x += a2.x; av.y += a2.y; av.z += a2.z; av.w += a2.w;
      }
      float4 bv = *(const float4*)(W + (long)(n0+row)*DD + k0 + sk4);
      u16 h0,l0,h1,l1,h2,l2,h3,l3;
      split2(av.x,h0,l0); split2(av.y,h1,l1); split2(av.z,h2,l2); split2(av.w,h3,l3);
      *(u16x4*)&Ah[row][sk4] = (u16x4){h0,h1,h2,h3};
      *(u16x4*)&Al[row][sk4] = (u16x4){l0,l1,l2,l3};
      split2(bv.x,h0,l0); split2(bv.y,h1,l1); split2(bv.z,h2,l2); split2(bv.w,h3,l3);
      *(u16x4*)&Bh[row][sk4] = (u16x4){h0,h1,h2,h3};
      *(u16x4*)&Bl[row][sk4] = (u16x4){l0,l1,l2,l3};
    }
    __syncthreads();
    s16x8 bh[4], bl[4];
    #pragma unroll
    for (int fn = 0; fn < 4; fn++){
      const int br = wn*64 + fn*16 + ln;
      bh[fn] = *(const s16x8*)&Bh[br][lg*8];
      bl[fn] = *(const s16x8*)&Bl[br][lg*8];
    }
    #pragma unroll
    for (int fm = 0; fm < 2; fm++){
      const int ar = wm*32 + fm*16 + ln;
      s16x8 ah = *(const s16x8*)&Ah[ar][lg*8];
      s16x8 al = *(const s16x8*)&Al[ar][lg*8];
      #pragma unroll
      for (int fn = 0; fn < 4; fn++){
        f32x4 c = acc[fm*4+fn];
        c = __builtin_amdgcn_mfma_f32_16x16x32_bf16(ah, bh[fn], c, 0, 0, 0);
        c = __builtin_amdgcn_mfma_f32_16x16x32_bf16(ah, bl[fn], c, 0, 0, 0);
        c = __builtin_amdgcn_mfma_f32_16x16x32_bf16(al, bh[fn], c, 0, 0, 0);
        acc[fm*4+fn] = c;
      }
    }
  }
  #pragma unroll
  for (int fm = 0; fm < 2; fm++){
    #pragma unroll
    for (int fn = 0; fn < 4; fn++){
      const int e = n0 + wn*64 + fn*16 + ln;
      const float bi = bias[e];
      #pragma unroll
      for (int r = 0; r < 4; r++){
        const int mm = m0 + wm*32 + fm*16 + lg*4 + r;
        out[(long)mm*DD + e] = acc[fm*4+fn][r] + bi;
      }
    }
  }
}

extern "C" void kernel_launch(void* const* d_in, const int* in_sizes, int n_in,
                              void* d_out, int out_size, void* d_ws, size_t ws_size,
                              hipStream_t stream)
{
  const float* x    = (const float*)d_in[0];
  const float* Wqkv = (const float*)d_in[1];
  const float* bqkv = (const float*)d_in[2];
  const float* Wo   = (const float*)d_in[3];
  const float* bo   = (const float*)d_in[4];
  float* out = (float*)d_out;

  const size_t QSZ = (size_t)BB*HH*SS*HD;   // 6,291,456 elems
  u16* Q  = (u16*)d_ws;
  u16* K  = Q + QSZ;
  u16* Vt = K + QSZ;                        // V^T [B,H,48,S]
  float* vals = (float*)(Vt + QSZ);         // fp32 partial-sum buffers

  const size_t need2 = 3*QSZ*sizeof(u16) + 2*QSZ*sizeof(float);  // 88.1 MB

  qkv_gemm<<<1152, 512, 0, stream>>>(x, Wqkv, bqkv, Q, K, Vt);
  if (ws_size >= need2){
    // 2-way key split: 1024 blocks -> 4 blocks/CU
    attn_kernel<<<1024, 512, 0, stream>>>(Q, K, Vt, vals, 1);
    out_gemm<<<384, 512, 0, stream>>>(vals, vals + QSZ, Wo, bo, out);
  } else {
    // proven round-9 configuration
    attn_kernel<<<512, 512, 0, stream>>>(Q, K, Vt, vals, 0);
    out_gemm<<<384, 512, 0, stream>>>(vals, nullptr, Wo, bo, out);
  }
}

// Round 11
// 236.270 us; speedup vs baseline: 1.0094x; 1.0094x over previous
//
#include <hip/hip_runtime.h>
#include <hip/hip_bf16.h>

#define BB 8
#define SS 2048
#define DD 384
#define HH 8
#define HD 48
#define QT 32
#define KT 64

typedef unsigned short u16;
typedef unsigned int u32;
typedef unsigned short u16x4 __attribute__((ext_vector_type(4)));
typedef unsigned short u16x8 __attribute__((ext_vector_type(8)));
typedef unsigned int u32x2 __attribute__((ext_vector_type(2)));
typedef short s16x8 __attribute__((ext_vector_type(8)));
typedef float f32x4 __attribute__((ext_vector_type(4)));

__device__ __forceinline__ float bf2f(u16 v){
  union { u32 u; float f; } x; x.u = ((u32)v) << 16; return x.f;
}
__device__ __forceinline__ u16 f2bf(float f){
  union { float f; u32 u; } x; x.f = f;
  u32 r = x.u + 0x7fffu + ((x.u >> 16) & 1u);
  return (u16)(r >> 16);
}
// split fp32 into hi (truncated bf16) + lo (bf16 of residual); hi+lo ~ 17-bit mantissa
__device__ __forceinline__ void split2(float f, u16& h, u16& l){
  union { float f; u32 u; } x; x.f = f;
  h = (u16)(x.u >> 16);
  l = f2bf(f - bf2f(h));
}
// pack two f32 -> two truncated bf16 in one u32 (lo = a, hi = b)
__device__ __forceinline__ u32 pack_trunc2(float a, float b){
  union { float f; u32 u; } xa, xb; xa.f = a; xb.f = b;
  return (xa.u >> 16) | (xb.u & 0xffff0000u);
}

// lgkm-only barrier: LDS writes visible, but global loads stay in flight
#define LBAR() do { \
  asm volatile("s_waitcnt lgkmcnt(0)" ::: "memory"); \
  __builtin_amdgcn_s_barrier(); \
  asm volatile("" ::: "memory"); \
} while (0)

// ---------------- Kernel 0: one-time hi/lo split of x, Wqkv, Wo ----------------
__global__ __launch_bounds__(256) void split_prep(
    const float* __restrict__ x, const float* __restrict__ Wq,
    const float* __restrict__ Wo,
    u16* __restrict__ xh, u16* __restrict__ xl,
    u16* __restrict__ wqh, u16* __restrict__ wql,
    u16* __restrict__ woh, u16* __restrict__ wol)
{
  const int N1 = (BB*SS*DD)/4, N2 = (3*DD*DD)/4, N3 = (DD*DD)/4;
  for (int i = blockIdx.x*blockDim.x + threadIdx.x; i < N1+N2+N3;
       i += gridDim.x*blockDim.x){
    const float4* src; u16 *dh, *dl; int off;
    if (i < N1){ src = (const float4*)x; dh = xh; dl = xl; off = i; }
    else if (i < N1+N2){ src = (const float4*)Wq; dh = wqh; dl = wql; off = i-N1; }
    else { src = (const float4*)Wo; dh = woh; dl = wol; off = i-N1-N2; }
    float4 v = src[off];
    u16 h0,l0,h1,l1,h2,l2,h3,l3;
    split2(v.x,h0,l0); split2(v.y,h1,l1); split2(v.z,h2,l2); split2(v.w,h3,l3);
    *(u16x4*)(dh + (long)off*4) = (u16x4){h0,h1,h2,h3};
    *(u16x4*)(dl + (long)off*4) = (u16x4){l0,l1,l2,l3};
  }
}

// ---------------- Kernel 1: QKV projection GEMM (pre-split bf16 inputs) ----------------
// Staging = 4x u16x8 global load + 4x ds_write_b128 per thread per k-step
// (zero split VALU); next-tile loads issued under MFMA; lgkm-only barriers
// keep them in flight. Scatter to Q (pre-scaled by log2(e)/sqrt(48)),
// K ([B,H,S,48]) and V^T ([B,H,48,S]) bf16 with bias.
__global__ __launch_bounds__(512, 4) void qkv_gemm2(
    const u16* __restrict__ xh, const u16* __restrict__ xl,
    const u16* __restrict__ Wh, const u16* __restrict__ Wl,
    const float* __restrict__ bias,
    u16* __restrict__ Q, u16* __restrict__ Kd, u16* __restrict__ Vt)
{
  __shared__ u16 Ah[128][40], Al[128][40], Bh[128][40], Bl[128][40];
  const int tid  = threadIdx.x;
  const int w    = tid >> 6, lane = tid & 63;
  const int lg   = lane >> 4, ln = lane & 15;
  const int wm   = w >> 1, wn = w & 1;
  const int mb   = blockIdx.x / 9, nb = blockIdx.x % 9;
  const int m0   = mb * 128, n0 = nb * 128;
  const int sr   = tid >> 2, so = (tid & 3) << 3;
  const float qscale = 0.2082350972f;  // log2(e)/sqrt(48)

  const u16* pah = xh + (long)(m0+sr)*DD + so;
  const u16* pal = xl + (long)(m0+sr)*DD + so;
  const u16* pbh = Wh + (long)(n0+sr)*DD + so;
  const u16* pbl = Wl + (long)(n0+sr)*DD + so;

  u16x8 ra = *(const u16x8*)(pah);
  u16x8 rl = *(const u16x8*)(pal);
  u16x8 rb = *(const u16x8*)(pbh);
  u16x8 rc = *(const u16x8*)(pbl);

  f32x4 acc[8];
  #pragma unroll
  for (int i = 0; i < 8; i++) acc[i] = (f32x4){0.f,0.f,0.f,0.f};

  for (int ks = 0; ks < 12; ks++){
    LBAR();   // prev iter's fragment reads done -> safe to overwrite LDS
    *(u16x8*)&Ah[sr][so] = ra;
    *(u16x8*)&Al[sr][so] = rl;
    *(u16x8*)&Bh[sr][so] = rb;
    *(u16x8*)&Bl[sr][so] = rc;
    LBAR();   // staged tile visible
    if (ks < 11){
      const int k1 = (ks+1) * 32;
      ra = *(const u16x8*)(pah + k1);
      rl = *(const u16x8*)(pal + k1);
      rb = *(const u16x8*)(pbh + k1);
      rc = *(const u16x8*)(pbl + k1);
    }
    s16x8 bh[4], bl[4];
    #pragma unroll
    for (int fn = 0; fn < 4; fn++){
      const int br = wn*64 + fn*16 + ln;
      bh[fn] = *(const s16x8*)&Bh[br][lg*8];
      bl[fn] = *(const s16x8*)&Bl[br][lg*8];
    }
    #pragma unroll
    for (int fm = 0; fm < 2; fm++){
      const int ar = wm*32 + fm*16 + ln;
      s16x8 ah = *(const s16x8*)&Ah[ar][lg*8];
      s16x8 al = *(const s16x8*)&Al[ar][lg*8];
      #pragma unroll
      for (int fn = 0; fn < 4; fn++){
        f32x4 c = acc[fm*4+fn];
        c = __builtin_amdgcn_mfma_f32_16x16x32_bf16(ah, bh[fn], c, 0, 0, 0);
        c = __builtin_amdgcn_mfma_f32_16x16x32_bf16(ah, bl[fn], c, 0, 0, 0);
        c = __builtin_amdgcn_mfma_f32_16x16x32_bf16(al, bh[fn], c, 0, 0, 0);
        acc[fm*4+fn] = c;
      }
    }
  }
  // epilogue: row = lg*4+r (M=token), col = ln (N=e); scatter
  #pragma unroll
  for (int fm = 0; fm < 2; fm++){
    #pragma unroll
    for (int fn = 0; fn < 4; fn++){
      const int e = n0 + wn*64 + fn*16 + ln;
      const float bi = bias[e];
      const int h = e / 144, c = e % 144;
      #pragma unroll
      for (int r = 0; r < 4; r++){
        const int mm = m0 + wm*32 + fm*16 + lg*4 + r;
        const int bb = mm >> 11, s = mm & 2047;
        const float v = acc[fm*4+fn][r] + bi;
        if (c < 48)       Q[(((long)(bb*HH + h))*SS + s)*HD + c] = f2bf(v * qscale);
        else if (c < 96)  Kd[(((long)(bb*HH + h))*SS + s)*HD + (c-48)] = f2bf(v);
        else              Vt[(((long)(bb*HH + h))*HD + (c-96))*SS + s] = f2bf(v);
      }
    }
  }
}

// ---------------- Kernel 2: MFMA attention with head-softmax, KT=64 ----------------
// Proven round-6/9 structure, widened to 64 keys per barrier pair:
// 32 iterations, 2 lgkm-only barriers each (was 64 iters / 128 barriers).
// K/V fragments issued at iteration top (no reg double-buffer: VGPR budget);
// softmax reads/writes b64 packed quads. Arithmetic order identical to
// round 9 -> bitwise-same output.
__global__ __launch_bounds__(512, 4) void attn_kernel(
    const u16* __restrict__ Q, const u16* __restrict__ K,
    const u16* __restrict__ Vg, float* __restrict__ vals)
{
  __shared__ u16 Ss[HH][QT][72];   // bf16 scores [h][q][64k+pad], 144B rows
  __shared__ u16 Pb[HH][QT][72];   // bf16 P [h][q][64k+pad]

  const int tid  = threadIdx.x;
  const int h    = tid >> 6;
  const int lane = tid & 63;
  // XCD-chunked swizzle: 512 blocks, 8 XCDs -> XCD x gets exactly batch b=x.
  const int wg   = ((int)blockIdx.x % 8) * 64 + (int)blockIdx.x / 8;
  const int b    = wg >> 6;
  const int qt   = wg & 63;
  const int q0   = qt * QT;
  const int lg   = lane >> 4;
  const int ln   = lane & 15;

  const long hbase = ((long)(b*HH + h)) * SS;
  const u16* vbase = Vg + ((long)(b*HH + h)) * HD * SS;
  const s16x8 z8 = (s16x8){0,0,0,0,0,0,0,0};

  // Q fragments (B operand of swapped QK^T) for both subtiles, held all kernel.
  s16x8 qf0[2], qf1[2];
  #pragma unroll
  for (int qs = 0; qs < 2; qs++){
    const u16* qp = Q + (hbase + q0 + qs*16 + ln)*HD;
    qf0[qs] = *(const s16x8*)(qp + lg*8);
    if (lane < 32) qf1[qs] = *(const s16x8*)(qp + 32 + lg*8);
    else           qf1[qs] = z8;
  }

  f32x4 oacc[2][3];
  #pragma unroll
  for (int qs = 0; qs < 2; qs++)
    #pragma unroll
    for (int c = 0; c < 3; c++) oacc[qs][c] = (f32x4){0.f,0.f,0.f,0.f};

  // softmax mapping: thread owns (q = tid>>4, k = smk4 .. smk4+3)
  const int smq = tid >> 4, smk4 = (tid & 15) << 2;

  for (int t = 0; t < SS/KT; t++){
    const int k0 = t * KT;

    // --- V fragments (6 x b128): issued now, consumed after both barriers ---
    s16x8 vf[3][2];
    #pragma unroll
    for (int c = 0; c < 3; c++)
      #pragma unroll
      for (int ksub = 0; ksub < 2; ksub++)
        vf[c][ksub] = *(const s16x8*)(vbase + (long)(c*16 + ln)*SS + k0 + ksub*32 + lg*8);

    // --- K fragments (4 subtiles): issued now, consumed by QK^T below ---
    s16x8 kfA[4], kfB[4];
    #pragma unroll
    for (int nt = 0; nt < 4; nt++){
      const u16* kp = K + (hbase + k0 + nt*16 + ln)*HD;
      kfA[nt] = *(const s16x8*)(kp + lg*8);
      if (lane < 32) kfB[nt] = *(const s16x8*)(kp + 32 + lg*8);
      else           kfB[nt] = z8;
    }

    // --- QK^T (swapped): D[k][q]; packed bf16 score writes (b64) ---
    __builtin_amdgcn_s_setprio(1);
    #pragma unroll
    for (int nt = 0; nt < 4; nt++){
      #pragma unroll
      for (int qs = 0; qs < 2; qs++){
        f32x4 a = (f32x4){0.f,0.f,0.f,0.f};
        a = __builtin_amdgcn_mfma_f32_16x16x32_bf16(kfA[nt], qf0[qs], a, 0, 0, 0);
        a = __builtin_amdgcn_mfma_f32_16x16x32_bf16(kfB[nt], qf1[qs], a, 0, 0, 0);
        u32x2 pw; pw[0] = pack_trunc2(a[0], a[1]); pw[1] = pack_trunc2(a[2], a[3]);
        *(u32x2*)&Ss[h][qs*16 + ln][nt*16 + lg*4] = pw;
      }
    }
    __builtin_amdgcn_s_setprio(0);
    LBAR();   // Ss visible; orders prev PV Pb-reads vs softmax writes

    // --- softmax over 8 heads; thread owns (smq, smk4..+3), b64 packed I/O ---
    {
      float e0[8], e1[8], e2[8], e3[8];
      float s0 = 0.f, s1 = 0.f, s2 = 0.f, s3 = 0.f;
      #pragma unroll
      for (int hh = 0; hh < 8; hh++){
        u32x2 wv = *(const u32x2*)&Ss[hh][smq][smk4];
        union { u32 u; float f; } a0, a1, a2, a3;
        a0.u = wv[0] << 16; a1.u = wv[0] & 0xffff0000u;
        a2.u = wv[1] << 16; a3.u = wv[1] & 0xffff0000u;
        e0[hh] = __builtin_amdgcn_exp2f(a0.f);
        e1[hh] = __builtin_amdgcn_exp2f(a1.f);
        e2[hh] = __builtin_amdgcn_exp2f(a2.f);
        e3[hh] = __builtin_amdgcn_exp2f(a3.f);
        s0 += e0[hh]; s1 += e1[hh]; s2 += e2[hh]; s3 += e3[hh];
      }
      float r0 = __builtin_amdgcn_rcpf(s0);
      float r1 = __builtin_amdgcn_rcpf(s1);
      float r2 = __builtin_amdgcn_rcpf(s2);
      float r3 = __builtin_amdgcn_rcpf(s3);
      #pragma unroll
      for (int hh = 0; hh < 8; hh++){
        u32x2 pw;
        pw[0] = pack_trunc2(e0[hh]*r0, e1[hh]*r1);
        pw[1] = pack_trunc2(e2[hh]*r2, e3[hh]*r3);
        *(u32x2*)&Pb[hh][smq][smk4] = pw;
      }
    }
    LBAR();   // Pb visible; orders softmax Ss-reads vs next-iter writes

    // --- PV: O[32q][48d] += P[32q][64k] * V[64k][48d] (V^T from registers) ---
    __builtin_amdgcn_s_setprio(1);
    #pragma unroll
    for (int qs = 0; qs < 2; qs++){
      #pragma unroll
      for (int ksub = 0; ksub < 2; ksub++){
        s16x8 pf = *(const s16x8*)&Pb[h][qs*16 + ln][ksub*32 + lg*8];
        oacc[qs][0] = __builtin_amdgcn_mfma_f32_16x16x32_bf16(pf, vf[0][ksub], oacc[qs][0], 0, 0, 0);
        oacc[qs][1] = __builtin_amdgcn_mfma_f32_16x16x32_bf16(pf, vf[1][ksub], oacc[qs][1], 0, 0, 0);
        oacc[qs][2] = __builtin_amdgcn_mfma_f32_16x16x32_bf16(pf, vf[2][ksub], oacc[qs][2], 0, 0, 0);
      }
    }
    __builtin_amdgcn_s_setprio(0);
  }

  // store vals[b][h][q][d] fp32 (bug-compatible flat layout)
  float* op = vals + (hbase + q0)*HD;
  #pragma unroll
  for (int qs = 0; qs < 2; qs++)
    #pragma unroll
    for (int c = 0; c < 3; c++)
      #pragma unroll
      for (int r = 0; r < 4; r++)
        op[(long)(qs*16 + lg*4 + r)*HD + c*16 + ln] = oacc[qs][c][r];
}

// ---------------- Kernel 3: output projection GEMM (f32 A, pre-split W) ----------------
__global__ __launch_bounds__(512, 4) void out_gemm2(
    const float* __restrict__ A,
    const u16* __restrict__ Wh, const u16* __restrict__ Wl,
    const float* __restrict__ bias, float* __restrict__ out)
{
  __shared__ u16 Ah[128][40], Al[128][40], Bh[128][40], Bl[128][40];
  const int tid  = threadIdx.x;
  const int w    = tid >> 6, lane = tid & 63;
  const int lg   = lane >> 4, ln = lane & 15;
  const int wm   = w >> 1, wn = w & 1;
  const int mb   = blockIdx.x / 3, nb = blockIdx.x % 3;
  const int m0   = mb * 128, n0 = nb * 128;
  const int srow = tid >> 3, sk4 = (tid & 7) << 2;   // A: f32 staging
  const int sr2  = tid >> 2, so2 = (tid & 3) << 3;   // B: bf16 staging

  f32x4 acc[8];
  #pragma unroll
  for (int i = 0; i < 8; i++) acc[i] = (f32x4){0.f,0.f,0.f,0.f};

  for (int ks = 0; ks < 12; ks++){
    const int k0 = ks * 32;
    __syncthreads();
    #pragma unroll
    for (int p = 0; p < 2; p++){
      const int row = srow + p*64;
      float4 av = *(const float4*)(A + (long)(m0+row)*DD + k0 + sk4);
      u16 h0,l0,h1,l1,h2,l2,h3,l3;
      split2(av.x,h0,l0); split2(av.y,h1,l1); split2(av.z,h2,l2); split2(av.w,h3,l3);
      *(u16x4*)&Ah[row][sk4] = (u16x4){h0,h1,h2,h3};
      *(u16x4*)&Al[row][sk4] = (u16x4){l0,l1,l2,l3};
    }
    *(u16x8*)&Bh[sr2][so2] = *(const u16x8*)(Wh + (long)(n0+sr2)*DD + k0 + so2);
    *(u16x8*)&Bl[sr2][so2] = *(const u16x8*)(Wl + (long)(n0+sr2)*DD + k0 + so2);
    __syncthreads();
    s16x8 bh[4], bl[4];
    #pragma unroll
    for (int fn = 0; fn < 4; fn++){
      const int br = wn*64 + fn*16 + ln;
      bh[fn] = *(const s16x8*)&Bh[br][lg*8];
      bl[fn] = *(const s16x8*)&Bl[br][lg*8];
    }
    #pragma unroll
    for (int fm = 0; fm < 2; fm++){
      const int ar = wm*32 + fm*16 + ln;
      s16x8 ah = *(const s16x8*)&Ah[ar][lg*8];
      s16x8 al = *(const s16x8*)&Al[ar][lg*8];
      #pragma unroll
      for (int fn = 0; fn < 4; fn++){
        f32x4 c = acc[fm*4+fn];
        c = __builtin_amdgcn_mfma_f32_16x16x32_bf16(ah, bh[fn], c, 0, 0, 0);
        c = __builtin_amdgcn_mfma_f32_16x16x32_bf16(ah, bl[fn], c, 0, 0, 0);
        c = __builtin_amdgcn_mfma_f32_16x16x32_bf16(al, bh[fn], c, 0, 0, 0);
        acc[fm*4+fn] = c;
      }
    }
  }
  #pragma unroll
  for (int fm = 0; fm < 2; fm++){
    #pragma unroll
    for (int fn = 0; fn < 4; fn++){
      const int e = n0 + wn*64 + fn*16 + ln;
      const float bi = bias[e];
      #pragma unroll
      for (int r = 0; r < 4; r++){
        const int mm = m0 + wm*32 + fm*16 + lg*4 + r;
        out[(long)mm*DD + e] = acc[fm*4+fn][r] + bi;
      }
    }
  }
}

extern "C" void kernel_launch(void* const* d_in, const int* in_sizes, int n_in,
                              void* d_out, int out_size, void* d_ws, size_t ws_size,
                              hipStream_t stream)
{
  const float* x    = (const float*)d_in[0];
  const float* Wqkv = (const float*)d_in[1];
  const float* bqkv = (const float*)d_in[2];
  const float* Wo   = (const float*)d_in[3];
  const float* bo   = (const float*)d_in[4];
  float* out = (float*)d_out;

  const size_t QSZ  = (size_t)BB*HH*SS*HD;  // 6,291,456 elems
  const size_t WQSZ = (size_t)3*DD*DD;
  const size_t WOSZ = (size_t)DD*DD;
  u16* Q   = (u16*)d_ws;
  u16* K   = Q + QSZ;
  u16* Vt  = K + QSZ;                       // V^T [B,H,48,S]
  u16* xh  = Vt + QSZ;                      // x hi plane (dead after qkv_gemm2)
  u16* xl  = xh + QSZ;                      // x lo plane
  float* vals = (float*)xh;                 // aliases xh+xl (25.2 MB)
  u16* wqh = xl + QSZ;
  u16* wql = wqh + WQSZ;
  u16* woh = wql + WQSZ;
  u16* wol = woh + WOSZ;
  // total ~65.3 MB; ws_size proven >= 88 MB in round 10

  split_prep<<<2048, 256, 0, stream>>>(x, Wqkv, Wo, xh, xl, wqh, wql, woh, wol);
  qkv_gemm2<<<1152, 512, 0, stream>>>(xh, xl, wqh, wql, bqkv, Q, K, Vt);
  attn_kernel<<<512, 512, 0, stream>>>(Q, K, Vt, vals);
  out_gemm2<<<384, 512, 0, stream>>>(vals, woh, wol, bo, out);
}